// Round 9
// baseline (58.191 us; speedup 1.0000x reference)
//
#include <hip/hip_runtime.h>

#define NBINS 10
#define NG 4
#define NH (NG * NBINS)      // 40
#define TPB 128              // 2 waves; each thread owns a private LDS column
#define NBLOCKS 2048         // 8 blocks/CU * 256 CU; LDS 20KB -> exactly 8/CU
#define PACKF 32.0f          // acc = 32*n + U; n<=32/column, U<32 -> exact unpack

// Single packed LDS RMW per sample. With pitch == radius (0.1):
//   h[j] = 0.1*(n_j - U_j + U_{j-1}),  n_j = #{floor-bin==j}, U_j = sum(u),
// where p = 10*(sigmoid(x)-1e-4), j0 = floor(p), u = p - j0 in [0,1).
// Column layout: addr = row*TPB + tid -> bank = tid%32, 2 lanes/bank per
// wave = conflict-free (free per m136).
__device__ __forceinline__ void proc1(float x, int g, float* col) {
    float ex = __expf(-x);                          // TRANS
    float rc = __builtin_amdgcn_rcpf(1.0f + ex);    // TRANS; sigmoid(x)
    float p  = __builtin_fmaf(rc, 10.0f, -0.001f);  // 10*(sigmoid - 1e-4)
    float fj = floorf(p);
    float u  = p - fj;                              // [0,1)
    int j0 = max((int)fj, 0);                       // -1: P~2e-20, clamp
    int row = g * NBINS + j0;
    col[row * TPB] += (PACKF + u);                  // one dependent RMW
}

__device__ __forceinline__ void proc4(float4 a, int4 g, float* col) {
    proc1(a.x, g.x, col); proc1(a.y, g.y, col);
    proc1(a.z, g.z, col); proc1(a.w, g.w, col);
}

__global__ void __launch_bounds__(TPB) wb_fused(const float4* __restrict__ acts,
                                                const int4* __restrict__ labels,
                                                const float* __restrict__ acts_s,
                                                const int* __restrict__ labels_s,
                                                const float* __restrict__ bary,
                                                float* __restrict__ out,
                                                float* __restrict__ parts,
                                                unsigned int* __restrict__ ticket,
                                                int n4, int n) {
    __shared__ float lh[NH * TPB];          // exactly 20 KB -> 8 blocks/CU
    // scalar aliases carved from lh; used only after lh's hist phase is dead
    float* hist   = &lh[0];                 // [NH]   (finale only)
    float* losses = &lh[48];                // [NG]   (finale only)
    volatile unsigned int* lastflag = (volatile unsigned int*)&lh[56];

    const int tid = threadIdx.x;
    #pragma unroll
    for (int i = 0; i < NH; ++i) lh[i * TPB + tid] = 0.0f;
    __syncthreads();

    float* col = &lh[tid];
    const int gsz = gridDim.x * TPB;        // 262144 threads
    int idx = blockIdx.x * TPB + tid;
    // 8 loads (128 B/lane) in flight; for N=8.4M this runs exactly 2 iterations
    for (; idx + 3 * gsz < n4; idx += 4 * gsz) {
        float4 a0 = acts[idx];
        float4 a1 = acts[idx + gsz];
        float4 a2 = acts[idx + 2 * gsz];
        float4 a3 = acts[idx + 3 * gsz];
        int4 g0 = labels[idx];
        int4 g1 = labels[idx + gsz];
        int4 g2 = labels[idx + 2 * gsz];
        int4 g3 = labels[idx + 3 * gsz];
        proc4(a0, g0, col); proc4(a1, g1, col);
        proc4(a2, g2, col); proc4(a3, g3, col);
    }
    for (; idx < n4; idx += gsz) proc4(acts[idx], labels[idx], col);

    // scalar tail for N % 4 != 0 (not hit for N = 8388608)
    if (blockIdx.x == 0 && tid == 0) {
        for (int i = n4 * 4; i < n; ++i) proc1(acts_s[i], labels_s[i], col);
    }
    __syncthreads();

    // Per-block epilogue: unpack columns (n = floor(acc/32), U = acc - 32n),
    // fold U_{j-1} via shfl_up (rows 0..39 live in wave 0), then publish this
    // block's histogram contribution via relaxed AGENT-scope atomic STORES:
    // write-through past the non-coherent XCD L2, unique slots, no RMW,
    // and no fences -> no L2 writeback/invalidate anywhere (R6-validated).
    if (tid < NH) {
        float n_sum = 0.0f, u_sum = 0.0f;
        for (int k = 0; k < TPB; ++k) {     // skewed start: <=2-way bank alias
            float acc = lh[tid * TPB + ((tid + k) & (TPB - 1))];
            float nc = floorf(acc * (1.0f / PACKF));
            n_sum += nc;
            u_sum += acc - PACKF * nc;
        }
        float u_prev = __shfl_up(u_sum, 1);
        if ((tid % NBINS) == 0) u_prev = 0.0f;
        float hb = 0.1f * (n_sum - u_sum + u_prev);
        __hip_atomic_store(&parts[tid * NBLOCKS + blockIdx.x], hb,
                           __ATOMIC_RELAXED, __HIP_MEMORY_SCOPE_AGENT);
    }
    __syncthreads();   // compiler emits s_waitcnt vmcnt(0) before s_barrier:
                       // this block's write-through stores reached the coherence point

    if (tid == 0) {
        unsigned int old = __hip_atomic_fetch_add(ticket, 1u, __ATOMIC_RELAXED,
                                                  __HIP_MEMORY_SCOPE_AGENT);
        *lastflag = (old == (unsigned int)(NBLOCKS - 1)) ? 1u : 0u;
    }
    __syncthreads();
    if (*lastflag == 0u) return;

    // ---- last block: global reduce + HistoBin norm + 1D OT ----
    // Agent-scope relaxed loads bypass this XCD's (possibly stale) L2.
    {
        int wave = tid >> 6, lane = tid & 63;
        for (int j = wave; j < NH; j += 2) {        // 2 waves, 20 rows each
            float s = 0.0f;
            #pragma unroll
            for (int k = 0; k < NBLOCKS / 64; ++k)  // 32 loads, all in flight
                s += __hip_atomic_load(&parts[j * NBLOCKS + lane + k * 64],
                                       __ATOMIC_RELAXED, __HIP_MEMORY_SCOPE_AGENT);
            #pragma unroll
            for (int off = 32; off; off >>= 1) s += __shfl_down(s, off);
            if (lane == 0) hist[j] = s;
        }
    }
    if (tid >= NH && tid < NH + NBINS)              // bary passthrough: out[1..10]
        out[1 + (tid - NH)] = bary[tid - NH];
    __syncthreads();

    if (tid < NG) {
        const int gI = tid;
        float h[NBINS];
        float s = 0.0f;
        #pragma unroll
        for (int j = 0; j < NBINS; ++j) { h[j] = hist[gI * NBINS + j] + 0.0001f; s += h[j]; }
        #pragma unroll
        for (int j = 0; j < NBINS; ++j) h[j] /= s;
        float s2 = 0.0f;                    // genHists renorm (fp no-op, kept for fidelity)
        #pragma unroll
        for (int j = 0; j < NBINS; ++j) s2 += h[j];
        #pragma unroll
        for (int j = 0; j < NBINS; ++j) h[j] /= s2;

        float cdfa[NBINS], cdfb[NBINS];
        float acc = 0.0f;
        #pragma unroll
        for (int j = 0; j < NBINS; ++j) { acc += h[j]; cdfa[j] = acc; }
        acc = 0.0f;
        #pragma unroll
        for (int j = 0; j < NBINS; ++j) { acc += bary[j]; cdfb[j] = acc; }
        // top-equalization reproduces searchsorted clip at q > min(top_a, top_b)
        float T = fmaxf(cdfa[NBINS - 1], cdfb[NBINS - 1]);
        cdfa[NBINS - 1] = T;
        cdfb[NBINS - 1] = T;

        // sum over merged quantile intervals == sum of pairwise interval overlaps
        float loss = 0.0f, lo_a = 0.0f;
        #pragma unroll
        for (int i = 0; i < NBINS; ++i) {
            float hi_a = cdfa[i];
            float lo_b = 0.0f;
            #pragma unroll
            for (int j = 0; j < NBINS; ++j) {
                float hi_b = cdfb[j];
                float ov = fminf(hi_a, hi_b) - fmaxf(lo_a, lo_b);
                float w = (float)((i - j) * (i - j));
                loss += fmaxf(ov, 0.0f) * w;
                lo_b = hi_b;
            }
            lo_a = hi_a;
        }
        losses[gI] = loss;
    }
    __syncthreads();
    if (tid == 0)
        out[0] = losses[0] + losses[1] + losses[2] + losses[3];
}

extern "C" void kernel_launch(void* const* d_in, const int* in_sizes, int n_in,
                              void* d_out, int out_size, void* d_ws, size_t ws_size,
                              hipStream_t stream) {
    const float* acts   = (const float*)d_in[0];
    const float* bary   = (const float*)d_in[1];
    const int*   labels = (const int*)d_in[2];
    float* outp = (float*)d_out;
    unsigned int* ticket = (unsigned int*)d_ws;                  // offset 0
    float* parts = (float*)((char*)d_ws + 256);                  // [NH][NBLOCKS] = 327 KB
    int N  = in_sizes[0];
    int n4 = N >> 2;

    hipMemsetAsync(ticket, 0, sizeof(unsigned int), stream);     // ticket only
    wb_fused<<<NBLOCKS, TPB, 0, stream>>>((const float4*)acts, (const int4*)labels,
                                          acts, labels, bary, outp,
                                          parts, ticket, n4, N);
}

// Round 10
// 34.677 us; speedup vs baseline: 1.6781x; 1.6781x over previous
//
#include <hip/hip_runtime.h>

#define NBINS 10
#define NG 4
#define NH (NG * NBINS)      // 40
#define TPB 128              // 2 waves; each thread owns a private LDS column
#define NBLOCKS 2048         // 8 blocks/CU * 256 CU; LDS 20KB -> exactly 8/CU
#define PACKF 32.0f          // acc = 32*n + U; n<=32/column, U<32 -> exact unpack
#define GRPSZ 32             // blocks per ticket group
#define NGRP (NBLOCKS / GRPSZ)   // 64 groups

// Single packed LDS RMW per sample. With pitch == radius (0.1):
//   h[j] = 0.1*(n_j - U_j + U_{j-1}),  n_j = #{floor-bin==j}, U_j = sum(u),
// where p = 10*(sigmoid(x)-1e-4), j0 = floor(p), u = p - j0 in [0,1).
// Column layout: addr = row*TPB + tid -> bank = tid%32, 2 lanes/bank per
// wave = conflict-free (free per m136).
__device__ __forceinline__ void proc1(float x, int g, float* col) {
    float ex = __expf(-x);                          // TRANS
    float rc = __builtin_amdgcn_rcpf(1.0f + ex);    // TRANS; sigmoid(x)
    float p  = __builtin_fmaf(rc, 10.0f, -0.001f);  // 10*(sigmoid - 1e-4)
    float fj = floorf(p);
    float u  = p - fj;                              // [0,1)
    int j0 = max((int)fj, 0);                       // -1: P~2e-20, clamp
    int row = g * NBINS + j0;
    col[row * TPB] += (PACKF + u);                  // one dependent RMW
}

__device__ __forceinline__ void proc4(float4 a, int4 g, float* col) {
    proc1(a.x, g.x, col); proc1(a.y, g.y, col);
    proc1(a.z, g.z, col); proc1(a.w, g.w, col);
}

__device__ __forceinline__ float ld_agent(const float* p) {
    return __hip_atomic_load(p, __ATOMIC_RELAXED, __HIP_MEMORY_SCOPE_AGENT);
}
__device__ __forceinline__ void st_agent(float* p, float v) {
    __hip_atomic_store(p, v, __ATOMIC_RELAXED, __HIP_MEMORY_SCOPE_AGENT);
}

__global__ void __launch_bounds__(TPB) wb_fused(const float4* __restrict__ acts,
                                                const int4* __restrict__ labels,
                                                const float* __restrict__ acts_s,
                                                const int* __restrict__ labels_s,
                                                const float* __restrict__ bary,
                                                float* __restrict__ out,
                                                float* __restrict__ parts,   // [NGRP][NH][GRPSZ]
                                                float* __restrict__ l1,      // [NH][NGRP]
                                                unsigned int* __restrict__ tickets,  // [NGRP] spaced 64
                                                unsigned int* __restrict__ ticket2,
                                                int n4, int n) {
    __shared__ float lh[NH * TPB];          // exactly 20 KB -> 8 blocks/CU
    // scalar aliases carved from lh; used only after lh's hist phase is dead
    float* hist   = &lh[0];                 // [NH]   (finale only)
    float* losses = &lh[48];                // [NG]   (finale only)
    volatile unsigned int* flag = (volatile unsigned int*)&lh[56];

    const int tid = threadIdx.x;
    #pragma unroll
    for (int i = 0; i < NH; ++i) lh[i * TPB + tid] = 0.0f;
    __syncthreads();

    float* col = &lh[tid];
    const int gsz = gridDim.x * TPB;        // 262144 threads
    int idx = blockIdx.x * TPB + tid;
    // 8 loads (128 B/lane) in flight; for N=8.4M this runs exactly 2 iterations
    for (; idx + 3 * gsz < n4; idx += 4 * gsz) {
        float4 a0 = acts[idx];
        float4 a1 = acts[idx + gsz];
        float4 a2 = acts[idx + 2 * gsz];
        float4 a3 = acts[idx + 3 * gsz];
        int4 g0 = labels[idx];
        int4 g1 = labels[idx + gsz];
        int4 g2 = labels[idx + 2 * gsz];
        int4 g3 = labels[idx + 3 * gsz];
        proc4(a0, g0, col); proc4(a1, g1, col);
        proc4(a2, g2, col); proc4(a3, g3, col);
    }
    for (; idx < n4; idx += gsz) proc4(acts[idx], labels[idx], col);

    // scalar tail for N % 4 != 0 (not hit for N = 8388608)
    if (blockIdx.x == 0 && tid == 0) {
        for (int i = n4 * 4; i < n; ++i) proc1(acts_s[i], labels_s[i], col);
    }
    __syncthreads();

    // Per-block epilogue: unpack columns (n = floor(acc/32), U = acc - 32n),
    // fold U_{j-1} via shfl_up (rows 0..39 live in wave 0); publish via
    // relaxed AGENT-scope atomic stores (write-through past non-coherent XCD
    // L2, unique slots, no fences -> no L2 invalidates; R6/R9-validated).
    const int grp = blockIdx.x >> 5, slot = blockIdx.x & (GRPSZ - 1);
    if (tid < NH) {
        float n_sum = 0.0f, u_sum = 0.0f;
        for (int k = 0; k < TPB; ++k) {     // skewed start: <=2-way bank alias
            float acc = lh[tid * TPB + ((tid + k) & (TPB - 1))];
            float nc = floorf(acc * (1.0f / PACKF));
            n_sum += nc;
            u_sum += acc - PACKF * nc;
        }
        float u_prev = __shfl_up(u_sum, 1);
        if ((tid % NBINS) == 0) u_prev = 0.0f;
        float hb = 0.1f * (n_sum - u_sum + u_prev);
        st_agent(&parts[(grp * NH + tid) * GRPSZ + slot], hb);
    }
    __syncthreads();   // s_waitcnt vmcnt(0) before s_barrier: stores at coherence point

    // ---- level-1 ticket: 32 same-address adds, 64 addresses in parallel ----
    if (tid == 0) {
        unsigned int old = __hip_atomic_fetch_add(&tickets[grp * 64], 1u,
                                                  __ATOMIC_RELAXED, __HIP_MEMORY_SCOPE_AGENT);
        *flag = (old == GRPSZ - 1) ? 1u : 0u;
    }
    __syncthreads();
    if (*flag == 0u) return;

    // ---- group leader: reduce this group's [NH][GRPSZ] slice -> l1[.][grp] ----
    if (tid < NH) {
        const float* src = &parts[(grp * NH + tid) * GRPSZ];
        float s = 0.0f;
        #pragma unroll
        for (int k = 0; k < GRPSZ; ++k) s += ld_agent(&src[k]);   // 32 in flight
        st_agent(&l1[tid * NGRP + grp], s);
    }
    __syncthreads();   // drain: l1 stores at coherence point

    // ---- level-2 ticket: 64 adds to one address ----
    if (tid == 0) {
        unsigned int old = __hip_atomic_fetch_add(ticket2, 1u,
                                                  __ATOMIC_RELAXED, __HIP_MEMORY_SCOPE_AGENT);
        *flag = (old == NGRP - 1) ? 1u : 0u;
    }
    __syncthreads();
    if (*flag == 0u) return;

    // ---- finale: reduce l1 + HistoBin norm + 1D OT ----
    if (tid < NH) {
        const float* src = &l1[tid * NGRP];
        float s = 0.0f;
        #pragma unroll
        for (int k = 0; k < NGRP; ++k) s += ld_agent(&src[k]);    // 64 in flight
        hist[tid] = s;
    }
    if (tid >= NH && tid < NH + NBINS)              // bary passthrough: out[1..10]
        out[1 + (tid - NH)] = bary[tid - NH];
    __syncthreads();

    if (tid < NG) {
        const int gI = tid;
        float h[NBINS];
        float s = 0.0f;
        #pragma unroll
        for (int j = 0; j < NBINS; ++j) { h[j] = hist[gI * NBINS + j] + 0.0001f; s += h[j]; }
        #pragma unroll
        for (int j = 0; j < NBINS; ++j) h[j] /= s;
        float s2 = 0.0f;                    // genHists renorm (fp no-op, kept for fidelity)
        #pragma unroll
        for (int j = 0; j < NBINS; ++j) s2 += h[j];
        #pragma unroll
        for (int j = 0; j < NBINS; ++j) h[j] /= s2;

        float cdfa[NBINS], cdfb[NBINS];
        float acc = 0.0f;
        #pragma unroll
        for (int j = 0; j < NBINS; ++j) { acc += h[j]; cdfa[j] = acc; }
        acc = 0.0f;
        #pragma unroll
        for (int j = 0; j < NBINS; ++j) { acc += bary[j]; cdfb[j] = acc; }
        // top-equalization reproduces searchsorted clip at q > min(top_a, top_b)
        float T = fmaxf(cdfa[NBINS - 1], cdfb[NBINS - 1]);
        cdfa[NBINS - 1] = T;
        cdfb[NBINS - 1] = T;

        // sum over merged quantile intervals == sum of pairwise interval overlaps
        float loss = 0.0f, lo_a = 0.0f;
        #pragma unroll
        for (int i = 0; i < NBINS; ++i) {
            float hi_a = cdfa[i];
            float lo_b = 0.0f;
            #pragma unroll
            for (int j = 0; j < NBINS; ++j) {
                float hi_b = cdfb[j];
                float ov = fminf(hi_a, hi_b) - fmaxf(lo_a, lo_b);
                float w = (float)((i - j) * (i - j));
                loss += fmaxf(ov, 0.0f) * w;
                lo_b = hi_b;
            }
            lo_a = hi_a;
        }
        losses[gI] = loss;
    }
    __syncthreads();
    if (tid == 0)
        out[0] = losses[0] + losses[1] + losses[2] + losses[3];
}

extern "C" void kernel_launch(void* const* d_in, const int* in_sizes, int n_in,
                              void* d_out, int out_size, void* d_ws, size_t ws_size,
                              hipStream_t stream) {
    const float* acts   = (const float*)d_in[0];
    const float* bary   = (const float*)d_in[1];
    const int*   labels = (const int*)d_in[2];
    float* outp = (float*)d_out;

    // ws layout: [0,16K) level-1 tickets (64, spaced 256B); [16K,16K+256) level-2
    // ticket; [32K, 32K+320K) parts [64][40][32]; then l1 [40][64].
    unsigned int* tickets = (unsigned int*)d_ws;
    unsigned int* ticket2 = (unsigned int*)((char*)d_ws + 16384);
    float* parts = (float*)((char*)d_ws + 32768);
    float* l1    = (float*)((char*)d_ws + 32768 + (size_t)NGRP * NH * GRPSZ * sizeof(float));
    int N  = in_sizes[0];
    int n4 = N >> 2;

    hipMemsetAsync(d_ws, 0, 16384 + 256, stream);    // tickets only
    wb_fused<<<NBLOCKS, TPB, 0, stream>>>((const float4*)acts, (const int4*)labels,
                                          acts, labels, bary, outp,
                                          parts, l1, tickets, ticket2, n4, N);
}

// Round 11
// 32.462 us; speedup vs baseline: 1.7926x; 1.0682x over previous
//
#include <hip/hip_runtime.h>

#define NBINS 10
#define NG 4
#define NH (NG * NBINS)      // 40
#define TPB 256              // 4 waves; each thread owns a private LDS column
#define NBLOCKS 2048         // 8 blocks/CU * 256 CU; LDS 20KB -> 8/CU = 32 waves/CU
#define NROWS2 (NH / 2)      // 20 dwords/column: 2 bins per dword (16-bit fields)
#define INVUQ (1.0f / 63.0f)

// One integer LDS RMW per sample. Two bins share a dword: field(row) at
// bit (row&1)*16, field = n<<11 | S_q, per-sample add = (1<<11) + u_q,
// u_q = round(u*63) <= 63. With <=19 samples/thread: field <= 19*2111 <
// 65536 -> no carry between fields, exact unpack.
//   h[j] = 0.1*(n_j - U_j + U_{j-1}),  U = S_q/63
// Column layout: word = dwrow*TPB + tid -> bank = tid%32, 2 lanes/bank
// per wave = conflict-free (free per m136).
__device__ __forceinline__ void proc1(float x, int g, unsigned int* col) {
    float ex = __expf(-x);                          // TRANS
    float rc = __builtin_amdgcn_rcpf(1.0f + ex);    // TRANS; sigmoid(x)
    float p  = __builtin_fmaf(rc, 10.0f, -0.001f);  // 10*(sigmoid - 1e-4)
    float fj = floorf(p);
    float u  = p - fj;                              // [0,1)
    int uq = (int)__builtin_fmaf(u, 63.0f, 0.5f);   // round(u*63), 0..63
    int j0 = max((int)fj, 0);                       // -1: P~2e-20, clamp
    int row = g * NBINS + j0;
    unsigned int val = (2048u + (unsigned)uq) << ((row & 1) << 4);
    col[(row >> 1) * TPB] += val;                   // one integer RMW
}

__device__ __forceinline__ void proc4(float4 a, int4 g, unsigned int* col) {
    proc1(a.x, g.x, col); proc1(a.y, g.y, col);
    proc1(a.z, g.z, col); proc1(a.w, g.w, col);
}

__global__ void __launch_bounds__(TPB) wb_hist(const float4* __restrict__ acts,
                                               const int4* __restrict__ labels,
                                               const float* __restrict__ acts_s,
                                               const int* __restrict__ labels_s,
                                               float* __restrict__ parts,
                                               int n4, int n, int nparts) {
    __shared__ unsigned int lh[NROWS2 * TPB];   // exactly 20 KB -> 8 blocks/CU
    const int tid = threadIdx.x;
    #pragma unroll
    for (int i = 0; i < NROWS2; ++i) lh[i * TPB + tid] = 0u;
    __syncthreads();

    unsigned int* col = &lh[tid];
    const int gsz = gridDim.x * TPB;            // 524288 threads
    int idx = blockIdx.x * TPB + tid;
    // 8 loads (128 B/lane) in flight; for N=8.4M this runs exactly once
    for (; idx + 3 * gsz < n4; idx += 4 * gsz) {
        float4 a0 = acts[idx];
        float4 a1 = acts[idx + gsz];
        float4 a2 = acts[idx + 2 * gsz];
        float4 a3 = acts[idx + 3 * gsz];
        int4 g0 = labels[idx];
        int4 g1 = labels[idx + gsz];
        int4 g2 = labels[idx + 2 * gsz];
        int4 g3 = labels[idx + 3 * gsz];
        proc4(a0, g0, col); proc4(a1, g1, col);
        proc4(a2, g2, col); proc4(a3, g3, col);
    }
    for (; idx < n4; idx += gsz) proc4(acts[idx], labels[idx], col);

    // scalar tail for N % 4 != 0 (not hit for N = 8388608; adds <=3 -> n<=19)
    if (blockIdx.x == 0 && tid == 0) {
        for (int i = n4 * 4; i < n; ++i) proc1(acts_s[i], labels_s[i], col);
    }
    __syncthreads();

    // Stage A: 160 threads = 4 column-chunks x 40 rows; each sums 64 columns.
    // Row pairs (2r,2r+1) read the same word (broadcast, free); skewed column
    // start keeps banks ~2-way.
    unsigned int nA = 0, sA = 0;
    if (tid < 160) {
        int row = tid % NH, chunk = tid / NH;
        int sh = (row & 1) << 4;
        const unsigned int* base = &lh[(row >> 1) * TPB + chunk * 64];
        #pragma unroll
        for (int k = 0; k < 64; ++k) {
            unsigned int f = (base[(row + k) & 63] >> sh) & 0xFFFFu;
            nA += f >> 11;
            sA += f & 0x7FFu;
        }
    }
    __syncthreads();                       // all lh reads complete
    if (tid < 160) lh[tid] = (nA << 16) | sA;   // nA<=1027, sA<=64512: both fit
    __syncthreads();

    // Stage B: 40 threads combine 4 chunks, fold U_{j-1} via shfl_up
    // (rows 0..39 live in wave 0), write per-block histogram contribution.
    if (tid < NH) {
        unsigned int n_sum = 0, s_sum = 0;
        #pragma unroll
        for (int c = 0; c < 4; ++c) {
            unsigned int f = lh[c * NH + tid];
            n_sum += f >> 16;
            s_sum += f & 0xFFFFu;
        }
        float u_sum = (float)s_sum * INVUQ;
        float u_prev = __shfl_up(u_sum, 1);
        if ((tid % NBINS) == 0) u_prev = 0.0f;
        parts[tid * nparts + blockIdx.x] = 0.1f * ((float)n_sum - u_sum + u_prev);
    }
}

__global__ void __launch_bounds__(1024) wb_final(const float4* __restrict__ parts4,
                                                 const float* __restrict__ bary,
                                                 float* __restrict__ out, int nparts) {
    __shared__ float hist[NH];
    __shared__ float bsh[NBINS];
    __shared__ float losses[NG];

    if (threadIdx.x < NBINS) {
        float b = bary[threadIdx.x];
        bsh[threadIdx.x] = b;
        out[1 + threadIdx.x] = b;     // tuple output: bary_est passthrough
    }

    // float4 reduce of [40][nparts] partials: each float4 = 4 partials, same bin
    const int q4 = nparts >> 2;
    int wave = threadIdx.x >> 6, lane = threadIdx.x & 63;
    for (int j = wave; j < NH; j += 16) {
        float s = 0.0f;
        for (int i = lane; i < q4; i += 64) {
            float4 v = parts4[j * q4 + i];
            s += (v.x + v.y) + (v.z + v.w);
        }
        #pragma unroll
        for (int off = 32; off; off >>= 1) s += __shfl_down(s, off);
        if (lane == 0) hist[j] = s;
    }
    __syncthreads();

    // 4 lanes (one per group), uniform control flow, all arrays register-resident
    if (threadIdx.x < NG) {
        const int gI = threadIdx.x;
        float h[NBINS];
        float s = 0.0f;
        #pragma unroll
        for (int j = 0; j < NBINS; ++j) { h[j] = hist[gI * NBINS + j] + 0.0001f; s += h[j]; }
        #pragma unroll
        for (int j = 0; j < NBINS; ++j) h[j] /= s;
        float s2 = 0.0f;                    // genHists renorm (fp no-op, kept for fidelity)
        #pragma unroll
        for (int j = 0; j < NBINS; ++j) s2 += h[j];
        #pragma unroll
        for (int j = 0; j < NBINS; ++j) h[j] /= s2;

        float cdfa[NBINS], cdfb[NBINS];
        float acc = 0.0f;
        #pragma unroll
        for (int j = 0; j < NBINS; ++j) { acc += h[j]; cdfa[j] = acc; }
        acc = 0.0f;
        #pragma unroll
        for (int j = 0; j < NBINS; ++j) { acc += bsh[j]; cdfb[j] = acc; }
        // top-equalization reproduces searchsorted clip at q > min(top_a, top_b)
        float T = fmaxf(cdfa[NBINS - 1], cdfb[NBINS - 1]);
        cdfa[NBINS - 1] = T;
        cdfb[NBINS - 1] = T;

        // sum over merged quantile intervals == sum of pairwise interval overlaps
        float loss = 0.0f, lo_a = 0.0f;
        #pragma unroll
        for (int i = 0; i < NBINS; ++i) {
            float hi_a = cdfa[i];
            float lo_b = 0.0f;
            #pragma unroll
            for (int j = 0; j < NBINS; ++j) {
                float hi_b = cdfb[j];
                float ov = fminf(hi_a, hi_b) - fmaxf(lo_a, lo_b);
                float w = (float)((i - j) * (i - j));
                loss += fmaxf(ov, 0.0f) * w;
                lo_b = hi_b;
            }
            lo_a = hi_a;
        }
        losses[gI] = loss;
    }
    __syncthreads();
    if (threadIdx.x == 0)
        out[0] = losses[0] + losses[1] + losses[2] + losses[3];
}

extern "C" void kernel_launch(void* const* d_in, const int* in_sizes, int n_in,
                              void* d_out, int out_size, void* d_ws, size_t ws_size,
                              hipStream_t stream) {
    const float* acts   = (const float*)d_in[0];
    const float* bary   = (const float*)d_in[1];
    const int*   labels = (const int*)d_in[2];
    float* outp  = (float*)d_out;
    float* parts = (float*)d_ws;           // [NH][NBLOCKS] = 327 KB, fully rewritten
    int N  = in_sizes[0];
    int n4 = N >> 2;

    wb_hist<<<NBLOCKS, TPB, 0, stream>>>((const float4*)acts, (const int4*)labels,
                                         acts, labels, parts, n4, N, NBLOCKS);
    wb_final<<<1, 1024, 0, stream>>>((const float4*)parts, bary, outp, NBLOCKS);
}

// Round 12
// 31.637 us; speedup vs baseline: 1.8393x; 1.0261x over previous
//
#include <hip/hip_runtime.h>

#define NBINS 10
#define NG 4
#define NH (NG * NBINS)      // 40
#define TPB 128              // 2 waves; each thread owns a private LDS column
#define NBLOCKS 2048         // 8 blocks/CU * 256 CU; LDS 20KB -> exactly 8/CU
#define PACKF 32.0f          // acc = 32*n + U; n<=32/column, U<32 -> exact unpack

// Single packed LDS RMW per sample. With pitch == radius (0.1):
//   h[j] = 0.1*(n_j - U_j + U_{j-1}),  n_j = #{floor-bin==j}, U_j = sum(u),
// where p = 10*(sigmoid(x)-1e-4), j0 = floor(p), u = p - j0 in [0,1).
// Column layout: addr = row*TPB + tid -> bank = tid%32, 2 lanes/bank per
// wave = conflict-free (free per m136).
__device__ __forceinline__ void proc1(float x, int g, float* col) {
    float ex = __expf(-x);                          // TRANS
    float rc = __builtin_amdgcn_rcpf(1.0f + ex);    // TRANS; sigmoid(x)
    float p  = __builtin_fmaf(rc, 10.0f, -0.001f);  // 10*(sigmoid - 1e-4)
    float fj = floorf(p);
    float u  = p - fj;                              // [0,1)
    int j0 = max((int)fj, 0);                       // -1: P~2e-20, clamp
    int row = g * NBINS + j0;
    col[row * TPB] += (PACKF + u);                  // one dependent RMW
}

__device__ __forceinline__ void proc4(float4 a, int4 g, float* col) {
    proc1(a.x, g.x, col); proc1(a.y, g.y, col);
    proc1(a.z, g.z, col); proc1(a.w, g.w, col);
}

__global__ void __launch_bounds__(TPB) wb_hist(const float4* __restrict__ acts,
                                               const int4* __restrict__ labels,
                                               const float* __restrict__ acts_s,
                                               const int* __restrict__ labels_s,
                                               float* __restrict__ parts,
                                               int n4, int n, int nparts) {
    __shared__ float lh[NH * TPB];          // exactly 20 KB -> 8 blocks/CU
    const int tid = threadIdx.x;
    #pragma unroll
    for (int i = 0; i < NH; ++i) lh[i * TPB + tid] = 0.0f;
    __syncthreads();

    float* col = &lh[tid];

    if (n4 == NBLOCKS * TPB * 8) {
        // CONTIGUOUS-SLICE path (the benchmark shape): block b owns float4s
        // [b*1024, b*1024+1024) of each array -> one 16 KB sequential run per
        // array per block (DRAM page locality), 16 loads (256 B/lane) in flight.
        const int base = blockIdx.x * (TPB * 8) + tid;
        float4 a0 = acts[base];
        float4 a1 = acts[base + TPB];
        float4 a2 = acts[base + 2 * TPB];
        float4 a3 = acts[base + 3 * TPB];
        float4 a4 = acts[base + 4 * TPB];
        float4 a5 = acts[base + 5 * TPB];
        float4 a6 = acts[base + 6 * TPB];
        float4 a7 = acts[base + 7 * TPB];
        int4 g0 = labels[base];
        int4 g1 = labels[base + TPB];
        int4 g2 = labels[base + 2 * TPB];
        int4 g3 = labels[base + 3 * TPB];
        int4 g4 = labels[base + 4 * TPB];
        int4 g5 = labels[base + 5 * TPB];
        int4 g6 = labels[base + 6 * TPB];
        int4 g7 = labels[base + 7 * TPB];
        proc4(a0, g0, col); proc4(a1, g1, col);
        proc4(a2, g2, col); proc4(a3, g3, col);
        proc4(a4, g4, col); proc4(a5, g5, col);
        proc4(a6, g6, col); proc4(a7, g7, col);
    } else {
        // generic fallback: R8-style strided batch loop
        const int gsz = gridDim.x * TPB;
        int idx = blockIdx.x * TPB + tid;
        for (; idx + 3 * gsz < n4; idx += 4 * gsz) {
            float4 a0 = acts[idx];
            float4 a1 = acts[idx + gsz];
            float4 a2 = acts[idx + 2 * gsz];
            float4 a3 = acts[idx + 3 * gsz];
            int4 g0 = labels[idx];
            int4 g1 = labels[idx + gsz];
            int4 g2 = labels[idx + 2 * gsz];
            int4 g3 = labels[idx + 3 * gsz];
            proc4(a0, g0, col); proc4(a1, g1, col);
            proc4(a2, g2, col); proc4(a3, g3, col);
        }
        for (; idx < n4; idx += gsz) proc4(acts[idx], labels[idx], col);
    }

    // scalar tail for N % 4 != 0 (not hit for N = 8388608)
    if (blockIdx.x == 0 && tid == 0) {
        for (int i = n4 * 4; i < n; ++i) proc1(acts_s[i], labels_s[i], col);
    }
    __syncthreads();

    // Per-block epilogue: unpack columns (n = floor(acc/32), U = acc - 32n),
    // fold U_{j-1} in via shfl_up (rows 0..39 live in wave 0), write direct
    // histogram contribution. No atomics, no fences.
    if (tid < NH) {
        float n_sum = 0.0f, u_sum = 0.0f;
        for (int k = 0; k < TPB; ++k) {     // skewed start: <=2-way bank alias
            float acc = lh[tid * TPB + ((tid + k) & (TPB - 1))];
            float nc = floorf(acc * (1.0f / PACKF));
            n_sum += nc;
            u_sum += acc - PACKF * nc;
        }
        float u_prev = __shfl_up(u_sum, 1);
        if ((tid % NBINS) == 0) u_prev = 0.0f;
        parts[tid * nparts + blockIdx.x] = 0.1f * (n_sum - u_sum + u_prev);
    }
}

__global__ void __launch_bounds__(1024) wb_final(const float4* __restrict__ parts4,
                                                 const float* __restrict__ bary,
                                                 float* __restrict__ out, int nparts) {
    __shared__ float hist[NH];
    __shared__ float bsh[NBINS];
    __shared__ float losses[NG];

    if (threadIdx.x < NBINS) {
        float b = bary[threadIdx.x];
        bsh[threadIdx.x] = b;
        out[1 + threadIdx.x] = b;     // tuple output: bary_est passthrough
    }

    // float4 reduce of [40][nparts] partials: each float4 = 4 partials, same bin
    const int q4 = nparts >> 2;
    int wave = threadIdx.x >> 6, lane = threadIdx.x & 63;
    for (int j = wave; j < NH; j += 16) {
        float s = 0.0f;
        for (int i = lane; i < q4; i += 64) {
            float4 v = parts4[j * q4 + i];
            s += (v.x + v.y) + (v.z + v.w);
        }
        #pragma unroll
        for (int off = 32; off; off >>= 1) s += __shfl_down(s, off);
        if (lane == 0) hist[j] = s;
    }
    __syncthreads();

    // 4 lanes (one per group), uniform control flow, all arrays register-resident
    if (threadIdx.x < NG) {
        const int gI = threadIdx.x;
        float h[NBINS];
        float s = 0.0f;
        #pragma unroll
        for (int j = 0; j < NBINS; ++j) { h[j] = hist[gI * NBINS + j] + 0.0001f; s += h[j]; }
        #pragma unroll
        for (int j = 0; j < NBINS; ++j) h[j] /= s;
        float s2 = 0.0f;                    // genHists renorm (fp no-op, kept for fidelity)
        #pragma unroll
        for (int j = 0; j < NBINS; ++j) s2 += h[j];
        #pragma unroll
        for (int j = 0; j < NBINS; ++j) h[j] /= s2;

        float cdfa[NBINS], cdfb[NBINS];
        float acc = 0.0f;
        #pragma unroll
        for (int j = 0; j < NBINS; ++j) { acc += h[j]; cdfa[j] = acc; }
        acc = 0.0f;
        #pragma unroll
        for (int j = 0; j < NBINS; ++j) { acc += bsh[j]; cdfb[j] = acc; }
        // top-equalization reproduces searchsorted clip at q > min(top_a, top_b)
        float T = fmaxf(cdfa[NBINS - 1], cdfb[NBINS - 1]);
        cdfa[NBINS - 1] = T;
        cdfb[NBINS - 1] = T;

        // sum over merged quantile intervals == sum of pairwise interval overlaps
        float loss = 0.0f, lo_a = 0.0f;
        #pragma unroll
        for (int i = 0; i < NBINS; ++i) {
            float hi_a = cdfa[i];
            float lo_b = 0.0f;
            #pragma unroll
            for (int j = 0; j < NBINS; ++j) {
                float hi_b = cdfb[j];
                float ov = fminf(hi_a, hi_b) - fmaxf(lo_a, lo_b);
                float w = (float)((i - j) * (i - j));
                loss += fmaxf(ov, 0.0f) * w;
                lo_b = hi_b;
            }
            lo_a = hi_a;
        }
        losses[gI] = loss;
    }
    __syncthreads();
    if (threadIdx.x == 0)
        out[0] = losses[0] + losses[1] + losses[2] + losses[3];
}

extern "C" void kernel_launch(void* const* d_in, const int* in_sizes, int n_in,
                              void* d_out, int out_size, void* d_ws, size_t ws_size,
                              hipStream_t stream) {
    const float* acts   = (const float*)d_in[0];
    const float* bary   = (const float*)d_in[1];
    const int*   labels = (const int*)d_in[2];
    float* outp  = (float*)d_out;
    float* parts = (float*)d_ws;           // [NH][NBLOCKS] = 327 KB, fully rewritten
    int N  = in_sizes[0];
    int n4 = N >> 2;

    wb_hist<<<NBLOCKS, TPB, 0, stream>>>((const float4*)acts, (const int4*)labels,
                                         acts, labels, parts, n4, N, NBLOCKS);
    wb_final<<<1, 1024, 0, stream>>>((const float4*)parts, bary, outp, NBLOCKS);
}

// Round 13
// 30.020 us; speedup vs baseline: 1.9384x; 1.0539x over previous
//
#include <hip/hip_runtime.h>

#define NBINS 10
#define NG 4
#define NH (NG * NBINS)      // 40
#define TPB 128              // 2 waves; each thread owns a private LDS column
#define NBLOCKS 2048         // 8 blocks/CU * 256 CU; LDS 20KB -> exactly 8/CU
#define PACKF 32.0f          // acc = 32*n + U; n<=32/column, U<32 -> exact unpack

typedef float f32x4 __attribute__((ext_vector_type(4)));
typedef int   i32x4 __attribute__((ext_vector_type(4)));

// Single packed LDS RMW per sample. With pitch == radius (0.1):
//   h[j] = 0.1*(n_j - U_j + U_{j-1}),  n_j = #{floor-bin==j}, U_j = sum(u),
// where p = 10*(sigmoid(x)-1e-4), j0 = floor(p), u = p - j0 in [0,1).
// Column layout: addr = row*TPB + tid -> bank = tid%32, 2 lanes/bank per
// wave = conflict-free (free per m136).
__device__ __forceinline__ void proc1(float x, int g, float* col) {
    float ex = __expf(-x);                          // TRANS
    float rc = __builtin_amdgcn_rcpf(1.0f + ex);    // TRANS; sigmoid(x)
    float p  = __builtin_fmaf(rc, 10.0f, -0.001f);  // 10*(sigmoid - 1e-4)
    float fj = floorf(p);
    float u  = p - fj;                              // [0,1)
    int j0 = max((int)fj, 0);                       // -1: P~2e-20, clamp
    int row = g * NBINS + j0;
    col[row * TPB] += (PACKF + u);                  // one dependent RMW
}

__device__ __forceinline__ void proc4(f32x4 a, i32x4 g, float* col) {
    proc1(a.x, g.x, col); proc1(a.y, g.y, col);
    proc1(a.z, g.z, col); proc1(a.w, g.w, col);
}

__global__ void __launch_bounds__(TPB) wb_hist(const f32x4* __restrict__ acts,
                                               const i32x4* __restrict__ labels,
                                               const float* __restrict__ acts_s,
                                               const int* __restrict__ labels_s,
                                               float* __restrict__ parts,
                                               int n4, int n, int nparts) {
    __shared__ float lh[NH * TPB];          // exactly 20 KB -> 8 blocks/CU
    const int tid = threadIdx.x;
    #pragma unroll
    for (int i = 0; i < NH; ++i) lh[i * TPB + tid] = 0.0f;
    __syncthreads();

    float* col = &lh[tid];
    const int gsz = gridDim.x * TPB;        // 262144 threads
    int idx = blockIdx.x * TPB + tid;
    // 8 NONTEMPORAL loads (128 B/lane) in flight: read-once stream, bypass
    // L1/L2 allocation -> no victim/writeback churn in the XCD L2s.
    for (; idx + 3 * gsz < n4; idx += 4 * gsz) {
        f32x4 a0 = __builtin_nontemporal_load(&acts[idx]);
        f32x4 a1 = __builtin_nontemporal_load(&acts[idx + gsz]);
        f32x4 a2 = __builtin_nontemporal_load(&acts[idx + 2 * gsz]);
        f32x4 a3 = __builtin_nontemporal_load(&acts[idx + 3 * gsz]);
        i32x4 g0 = __builtin_nontemporal_load(&labels[idx]);
        i32x4 g1 = __builtin_nontemporal_load(&labels[idx + gsz]);
        i32x4 g2 = __builtin_nontemporal_load(&labels[idx + 2 * gsz]);
        i32x4 g3 = __builtin_nontemporal_load(&labels[idx + 3 * gsz]);
        proc4(a0, g0, col); proc4(a1, g1, col);
        proc4(a2, g2, col); proc4(a3, g3, col);
    }
    for (; idx < n4; idx += gsz)
        proc4(__builtin_nontemporal_load(&acts[idx]),
              __builtin_nontemporal_load(&labels[idx]), col);

    // scalar tail for N % 4 != 0 (not hit for N = 8388608)
    if (blockIdx.x == 0 && tid == 0) {
        for (int i = n4 * 4; i < n; ++i) proc1(acts_s[i], labels_s[i], col);
    }
    __syncthreads();

    // Per-block epilogue: unpack columns (n = floor(acc/32), U = acc - 32n),
    // fold U_{j-1} in via shfl_up (rows 0..39 live in wave 0), write direct
    // histogram contribution. No atomics, no fences.
    if (tid < NH) {
        float n_sum = 0.0f, u_sum = 0.0f;
        for (int k = 0; k < TPB; ++k) {     // skewed start: <=2-way bank alias
            float acc = lh[tid * TPB + ((tid + k) & (TPB - 1))];
            float nc = floorf(acc * (1.0f / PACKF));
            n_sum += nc;
            u_sum += acc - PACKF * nc;
        }
        float u_prev = __shfl_up(u_sum, 1);
        if ((tid % NBINS) == 0) u_prev = 0.0f;
        parts[tid * nparts + blockIdx.x] = 0.1f * (n_sum - u_sum + u_prev);
    }
}

__global__ void __launch_bounds__(1024) wb_final(const float4* __restrict__ parts4,
                                                 const float* __restrict__ bary,
                                                 float* __restrict__ out, int nparts) {
    __shared__ float hist[NH];
    __shared__ float bsh[NBINS];
    __shared__ float losses[NG];

    if (threadIdx.x < NBINS) {
        float b = bary[threadIdx.x];
        bsh[threadIdx.x] = b;
        out[1 + threadIdx.x] = b;     // tuple output: bary_est passthrough
    }

    // float4 reduce of [40][nparts] partials: each float4 = 4 partials, same bin
    const int q4 = nparts >> 2;
    int wave = threadIdx.x >> 6, lane = threadIdx.x & 63;
    for (int j = wave; j < NH; j += 16) {
        float s = 0.0f;
        for (int i = lane; i < q4; i += 64) {
            float4 v = parts4[j * q4 + i];
            s += (v.x + v.y) + (v.z + v.w);
        }
        #pragma unroll
        for (int off = 32; off; off >>= 1) s += __shfl_down(s, off);
        if (lane == 0) hist[j] = s;
    }
    __syncthreads();

    // 4 lanes (one per group), uniform control flow, all arrays register-resident
    if (threadIdx.x < NG) {
        const int gI = threadIdx.x;
        float h[NBINS];
        float s = 0.0f;
        #pragma unroll
        for (int j = 0; j < NBINS; ++j) { h[j] = hist[gI * NBINS + j] + 0.0001f; s += h[j]; }
        #pragma unroll
        for (int j = 0; j < NBINS; ++j) h[j] /= s;
        float s2 = 0.0f;                    // genHists renorm (fp no-op, kept for fidelity)
        #pragma unroll
        for (int j = 0; j < NBINS; ++j) s2 += h[j];
        #pragma unroll
        for (int j = 0; j < NBINS; ++j) h[j] /= s2;

        float cdfa[NBINS], cdfb[NBINS];
        float acc = 0.0f;
        #pragma unroll
        for (int j = 0; j < NBINS; ++j) { acc += h[j]; cdfa[j] = acc; }
        acc = 0.0f;
        #pragma unroll
        for (int j = 0; j < NBINS; ++j) { acc += bsh[j]; cdfb[j] = acc; }
        // top-equalization reproduces searchsorted clip at q > min(top_a, top_b)
        float T = fmaxf(cdfa[NBINS - 1], cdfb[NBINS - 1]);
        cdfa[NBINS - 1] = T;
        cdfb[NBINS - 1] = T;

        // sum over merged quantile intervals == sum of pairwise interval overlaps
        float loss = 0.0f, lo_a = 0.0f;
        #pragma unroll
        for (int i = 0; i < NBINS; ++i) {
            float hi_a = cdfa[i];
            float lo_b = 0.0f;
            #pragma unroll
            for (int j = 0; j < NBINS; ++j) {
                float hi_b = cdfb[j];
                float ov = fminf(hi_a, hi_b) - fmaxf(lo_a, lo_b);
                float w = (float)((i - j) * (i - j));
                loss += fmaxf(ov, 0.0f) * w;
                lo_b = hi_b;
            }
            lo_a = hi_a;
        }
        losses[gI] = loss;
    }
    __syncthreads();
    if (threadIdx.x == 0)
        out[0] = losses[0] + losses[1] + losses[2] + losses[3];
}

extern "C" void kernel_launch(void* const* d_in, const int* in_sizes, int n_in,
                              void* d_out, int out_size, void* d_ws, size_t ws_size,
                              hipStream_t stream) {
    const float* acts   = (const float*)d_in[0];
    const float* bary   = (const float*)d_in[1];
    const int*   labels = (const int*)d_in[2];
    float* outp  = (float*)d_out;
    float* parts = (float*)d_ws;           // [NH][NBLOCKS] = 327 KB, fully rewritten
    int N  = in_sizes[0];
    int n4 = N >> 2;

    wb_hist<<<NBLOCKS, TPB, 0, stream>>>((const f32x4*)acts, (const i32x4*)labels,
                                         acts, labels, parts, n4, N, NBLOCKS);
    wb_final<<<1, 1024, 0, stream>>>((const float4*)parts, bary, outp, NBLOCKS);
}

// Round 14
// 29.615 us; speedup vs baseline: 1.9649x; 1.0137x over previous
//
#include <hip/hip_runtime.h>

#define NBINS 10
#define NG 4
#define NH (NG * NBINS)      // 40
#define TPB 128              // 2 waves; each thread owns a private LDS column
#define NBLOCKS 2048         // 8 blocks/CU * 256 CU; LDS 20KB -> exactly 8/CU
#define PACKF 32.0f          // acc = 32*n + U; n<=32/column, U<32 -> exact unpack

typedef float f32x4 __attribute__((ext_vector_type(4)));
typedef int   i32x4 __attribute__((ext_vector_type(4)));

// Single packed LDS RMW per sample. With pitch == radius (0.1):
//   h[j] = 0.1*(n_j - U_j + U_{j-1}),  n_j = #{floor-bin==j}, U_j = sum(u),
// where p = 10*(sigmoid(x)-1e-4), j0 = floor(p), u = p - j0 in [0,1).
// Column layout: addr = row*TPB + tid -> bank = tid%32, 2 lanes/bank per
// wave = conflict-free (free per m136).
__device__ __forceinline__ void proc1(float x, int g, float* col) {
    float ex = __expf(-x);
    float rc = __builtin_amdgcn_rcpf(1.0f + ex);
    float p  = __builtin_fmaf(rc, 10.0f, -0.001f);
    float fj = floorf(p);
    float u  = p - fj;
    int j0 = max((int)fj, 0);
    col[(g * NBINS + j0) * TPB] += (PACKF + u);
}

__global__ void __launch_bounds__(TPB, 4) wb_hist(const f32x4* __restrict__ acts,
                                                  const i32x4* __restrict__ labels,
                                                  const float* __restrict__ acts_s,
                                                  const int* __restrict__ labels_s,
                                                  float* __restrict__ parts,
                                                  int n4, int n, int nparts) {
    __shared__ float lh[NH * TPB];          // exactly 20 KB -> 8 blocks/CU
    const int tid = threadIdx.x;
    #pragma unroll
    for (int i = 0; i < NH; ++i) lh[i * TPB + tid] = 0.0f;
    __syncthreads();

    float* col = &lh[tid];

    if (n4 == NBLOCKS * TPB * 8) {
        // ---- PHASE-SPLIT path (benchmark shape: 32 samples/thread) ----
        // Phase 1: all 16 NT loads (contiguous 16 KB run per array per block).
        const int base = blockIdx.x * (TPB * 8) + tid;
        f32x4 a[8]; i32x4 g[8];
        #pragma unroll
        for (int k = 0; k < 8; ++k) a[k] = __builtin_nontemporal_load(&acts[base + k * TPB]);
        #pragma unroll
        for (int k = 0; k < 8; ++k) g[k] = __builtin_nontemporal_load(&labels[base + k * TPB]);

        // Phase 2: pure-VALU burst -> static register arrays (no DS ops, so
        // all of this issues while the loads drain; one vmcnt wait total).
        float uu[32]; int rr[32];
        #pragma unroll
        for (int k = 0; k < 8; ++k) {
            #pragma unroll
            for (int e = 0; e < 4; ++e) {
                float x = a[k][e];
                float ex = __expf(-x);
                float rc = __builtin_amdgcn_rcpf(1.0f + ex);
                float p  = __builtin_fmaf(rc, 10.0f, -0.001f);
                float fj = floorf(p);
                uu[k * 4 + e] = p - fj;
                rr[k * 4 + e] = g[k][e] * NBINS + max((int)fj, 0);
            }
        }

        // Phase 3: tight LDS RMW burst. lgkmcnt stalls here overlap with
        // other waves' phase-1/2 (waves desynchronize across the CU).
        #pragma unroll
        for (int s = 0; s < 32; ++s)
            col[rr[s] * TPB] += (PACKF + uu[s]);
    } else {
        // generic fallback: R13-style strided NT batch loop
        const int gsz = gridDim.x * TPB;
        int idx = blockIdx.x * TPB + tid;
        for (; idx + 3 * gsz < n4; idx += 4 * gsz) {
            f32x4 a0 = __builtin_nontemporal_load(&acts[idx]);
            f32x4 a1 = __builtin_nontemporal_load(&acts[idx + gsz]);
            f32x4 a2 = __builtin_nontemporal_load(&acts[idx + 2 * gsz]);
            f32x4 a3 = __builtin_nontemporal_load(&acts[idx + 3 * gsz]);
            i32x4 g0 = __builtin_nontemporal_load(&labels[idx]);
            i32x4 g1 = __builtin_nontemporal_load(&labels[idx + gsz]);
            i32x4 g2 = __builtin_nontemporal_load(&labels[idx + 2 * gsz]);
            i32x4 g3 = __builtin_nontemporal_load(&labels[idx + 3 * gsz]);
            #pragma unroll
            for (int e = 0; e < 4; ++e) proc1(a0[e], g0[e], col);
            #pragma unroll
            for (int e = 0; e < 4; ++e) proc1(a1[e], g1[e], col);
            #pragma unroll
            for (int e = 0; e < 4; ++e) proc1(a2[e], g2[e], col);
            #pragma unroll
            for (int e = 0; e < 4; ++e) proc1(a3[e], g3[e], col);
        }
        for (; idx < n4; idx += gsz) {
            f32x4 a = __builtin_nontemporal_load(&acts[idx]);
            i32x4 g = __builtin_nontemporal_load(&labels[idx]);
            #pragma unroll
            for (int e = 0; e < 4; ++e) proc1(a[e], g[e], col);
        }
    }

    // scalar tail for N % 4 != 0 (not hit for N = 8388608)
    if (blockIdx.x == 0 && tid == 0) {
        for (int i = n4 * 4; i < n; ++i) proc1(acts_s[i], labels_s[i], col);
    }
    __syncthreads();

    // Per-block epilogue: unpack columns (n = floor(acc/32), U = acc - 32n),
    // fold U_{j-1} in via shfl_up (rows 0..39 live in wave 0), write direct
    // histogram contribution. No atomics, no fences.
    if (tid < NH) {
        float n_sum = 0.0f, u_sum = 0.0f;
        for (int k = 0; k < TPB; ++k) {     // skewed start: <=2-way bank alias
            float acc = lh[tid * TPB + ((tid + k) & (TPB - 1))];
            float nc = floorf(acc * (1.0f / PACKF));
            n_sum += nc;
            u_sum += acc - PACKF * nc;
        }
        float u_prev = __shfl_up(u_sum, 1);
        if ((tid % NBINS) == 0) u_prev = 0.0f;
        parts[tid * nparts + blockIdx.x] = 0.1f * (n_sum - u_sum + u_prev);
    }
}

__global__ void __launch_bounds__(1024) wb_final(const float4* __restrict__ parts4,
                                                 const float* __restrict__ bary,
                                                 float* __restrict__ out, int nparts) {
    __shared__ float hist[NH];
    __shared__ float bsh[NBINS];
    __shared__ float losses[NG];

    if (threadIdx.x < NBINS) {
        float b = bary[threadIdx.x];
        bsh[threadIdx.x] = b;
        out[1 + threadIdx.x] = b;     // tuple output: bary_est passthrough
    }

    // float4 reduce of [40][nparts] partials: each float4 = 4 partials, same bin
    const int q4 = nparts >> 2;
    int wave = threadIdx.x >> 6, lane = threadIdx.x & 63;
    for (int j = wave; j < NH; j += 16) {
        float s = 0.0f;
        for (int i = lane; i < q4; i += 64) {
            float4 v = parts4[j * q4 + i];
            s += (v.x + v.y) + (v.z + v.w);
        }
        #pragma unroll
        for (int off = 32; off; off >>= 1) s += __shfl_down(s, off);
        if (lane == 0) hist[j] = s;
    }
    __syncthreads();

    // 4 lanes (one per group), uniform control flow, all arrays register-resident
    if (threadIdx.x < NG) {
        const int gI = threadIdx.x;
        float h[NBINS];
        float s = 0.0f;
        #pragma unroll
        for (int j = 0; j < NBINS; ++j) { h[j] = hist[gI * NBINS + j] + 0.0001f; s += h[j]; }
        #pragma unroll
        for (int j = 0; j < NBINS; ++j) h[j] /= s;
        float s2 = 0.0f;                    // genHists renorm (fp no-op, kept for fidelity)
        #pragma unroll
        for (int j = 0; j < NBINS; ++j) s2 += h[j];
        #pragma unroll
        for (int j = 0; j < NBINS; ++j) h[j] /= s2;

        float cdfa[NBINS], cdfb[NBINS];
        float acc = 0.0f;
        #pragma unroll
        for (int j = 0; j < NBINS; ++j) { acc += h[j]; cdfa[j] = acc; }
        acc = 0.0f;
        #pragma unroll
        for (int j = 0; j < NBINS; ++j) { acc += bsh[j]; cdfb[j] = acc; }
        // top-equalization reproduces searchsorted clip at q > min(top_a, top_b)
        float T = fmaxf(cdfa[NBINS - 1], cdfb[NBINS - 1]);
        cdfa[NBINS - 1] = T;
        cdfb[NBINS - 1] = T;

        // sum over merged quantile intervals == sum of pairwise interval overlaps
        float loss = 0.0f, lo_a = 0.0f;
        #pragma unroll
        for (int i = 0; i < NBINS; ++i) {
            float hi_a = cdfa[i];
            float lo_b = 0.0f;
            #pragma unroll
            for (int j = 0; j < NBINS; ++j) {
                float hi_b = cdfb[j];
                float ov = fminf(hi_a, hi_b) - fmaxf(lo_a, lo_b);
                float w = (float)((i - j) * (i - j));
                loss += fmaxf(ov, 0.0f) * w;
                lo_b = hi_b;
            }
            lo_a = hi_a;
        }
        losses[gI] = loss;
    }
    __syncthreads();
    if (threadIdx.x == 0)
        out[0] = losses[0] + losses[1] + losses[2] + losses[3];
}

extern "C" void kernel_launch(void* const* d_in, const int* in_sizes, int n_in,
                              void* d_out, int out_size, void* d_ws, size_t ws_size,
                              hipStream_t stream) {
    const float* acts   = (const float*)d_in[0];
    const float* bary   = (const float*)d_in[1];
    const int*   labels = (const int*)d_in[2];
    float* outp  = (float*)d_out;
    float* parts = (float*)d_ws;           // [NH][NBLOCKS] = 327 KB, fully rewritten
    int N  = in_sizes[0];
    int n4 = N >> 2;

    wb_hist<<<NBLOCKS, TPB, 0, stream>>>((const f32x4*)acts, (const i32x4*)labels,
                                         acts, labels, parts, n4, N, NBLOCKS);
    wb_final<<<1, 1024, 0, stream>>>((const float4*)parts, bary, outp, NBLOCKS);
}